// Round 4
// baseline (467.545 us; speedup 1.0000x reference)
//
#include <hip/hip_runtime.h>
#include <hip/hip_cooperative_groups.h>

namespace cg = cooperative_groups;

#define MAXLEN 100
#define HDIM 64
#define CH 4                       // x-staging chunk length (steps)
#define NSEG 12                    // segments per block (12 real rows of 16)
#define SROW 72                    // ushorts per bf16 x step-row (144 B)
#define SPLANE (CH * SROW + 8)     // 296 ushorts per segment plane
#define HSTR 72                    // ushorts per h row (144 B)
#define L2E 1.44269504f

typedef __attribute__((ext_vector_type(8))) short bf16x8;
typedef __attribute__((ext_vector_type(4))) float f32x4;

// Step barrier: LDS-only consistency (no implicit vmcnt(0) drain), so the
// chunk-ahead x prefetch stays in flight across all step barriers.
#define LGKM_BARRIER() asm volatile("s_waitcnt lgkmcnt(0)\n\ts_barrier" ::: "memory")

// RNE f32x2 -> packed bf16x2 in one instruction (no builtin on gfx950).
__device__ __forceinline__ unsigned cvtpk(float a, float b) {
    unsigned r;
    asm("v_cvt_pk_bf16_f32 %0, %1, %2" : "=v"(r) : "v"(a), "v"(b));
    return r;
}
__device__ __forceinline__ bf16x8 pack8(f32x4 a, f32x4 b) {
    union { unsigned u[4]; bf16x8 v; } c;
    c.u[0] = cvtpk(a[0], a[1]); c.u[1] = cvtpk(a[2], a[3]);
    c.u[2] = cvtpk(b[0], b[1]); c.u[3] = cvtpk(b[2], b[3]);
    return c.v;
}
// Activations on PRE-SCALED pre-activations: -L2E (resp -2*L2E for gate g)
// is folded into the bf16 weights; the scaled bias is the MFMA C-seed.
__device__ __forceinline__ float sig_pre(float a) {     // a = -L2E*z
    return __builtin_amdgcn_rcpf(1.0f + __builtin_amdgcn_exp2f(a));
}
__device__ __forceinline__ float tanh_pre(float a) {    // a = -2*L2E*z
    return fmaf(2.0f, __builtin_amdgcn_rcpf(1.0f + __builtin_amdgcn_exp2f(a)), -1.0f);
}
__device__ __forceinline__ float tanh_p(float v) {      // v in true scale
    return fmaf(2.0f, __builtin_amdgcn_rcpf(1.0f + __builtin_amdgcn_exp2f(v * (-2.0f * L2E))), -1.0f);
}

// Single cooperative dispatch: in-kernel counting sort of segments by length
// (descending) across 3 grid.sync()s, then the proven R2 main loop (80.6 us).
// Sorting makes each block's 12 segments ~equal length (lmax ~= mean, not
// max-of-12: -17% steps) and staggers block finishes; doing it IN-kernel
// removes the ~50 us cost of the 3-dispatch pre-pass chain (R2's mistake).
// Fallback (doSort=0, plain launch): per-block binary search, unsorted.
//
// Main loop: 683 blocks x 256 threads; 12 segments/block; 4 waves, wave w
// owns hidden cols [16w,16w+16) for all 4 gates. Segment s -> MFMA A/C row
// (s/3)*4+(s%3); each lane's C regs 0..2 are its 3 real (seg,hid) bundles.
// Per-step MFMA chain split: accx[g] = x_t @ Wih' (h-independent, seeded with
// the scaled bias) runs in the previous step's trans shadow; the serial step
// is acc = mfma(ha1,wh1, mfma(ha0,wh0,accx)).
__global__ __launch_bounds__(256, 3)
void lstm_coop_kernel(const float* __restrict__ x,
                      const float* __restrict__ Wih,
                      const float* __restrict__ Whh,
                      const float* __restrict__ bih,
                      const float* __restrict__ bhh,
                      const int* __restrict__ index,
                      int* ws, float* __restrict__ out,
                      int N, int B, int doSort) {
    const int tid  = threadIdx.x;
    const int w    = tid >> 6;
    const int lane = tid & 63;
    const int l15  = lane & 15;
    const int quad = lane >> 4;
    const int segbase = blockIdx.x * NSEG;
    const int ncol = w * 16 + l15;

    __shared__ __align__(16) unsigned short xst[NSEG * SPLANE];  // 7.1 KB
    __shared__ __align__(16) unsigned short hst[2][16][HSTR];    // 4.6 KB
    __shared__ int sstart[NSEG], slen[NSEG], sseg[NSEG];
    __shared__ int hist_s[MAXLEN + 1], base_s[MAXLEN + 1];

    // ---- Phase S: in-kernel counting sort (cooperative path only) ----
    const int2* sp = nullptr;
    if (doSort) {
        cg::grid_group grid = cg::this_grid();
        int* hist = ws;                       // [101] (padded to 128)
        int* cnt  = ws + 128;                 // [101] (padded to 128)
        int2* slotPacked = (int2*)(ws + 256);
        const int gid = blockIdx.x * 256 + tid;
        const int nslots = (int)gridDim.x * NSEG;

        int myS0 = 0, myLen = 0;
        if (gid < 256) ws[gid] = 0;           // zero hist + cnt
        if (gid < B) {                        // own bounds, kept in registers
            int lo = 0, hi = N;
            while (lo < hi) { int m = (lo + hi) >> 1; if (index[m] < gid) lo = m + 1; else hi = m; }
            myS0 = lo;
            int l2 = lo, h2 = N;
            while (l2 < h2) { int m = (l2 + h2) >> 1; if (index[m] < gid + 1) l2 = m + 1; else h2 = m; }
            myLen = l2 - lo;
            myLen = myLen < MAXLEN ? myLen : MAXLEN;
        }
        grid.sync();                          // hist/cnt zeroed
        if (gid < B) atomicAdd(&hist[myLen], 1);
        grid.sync();                          // hist complete
        if (tid <= MAXLEN) hist_s[tid] = hist[tid];
        __syncthreads();
        if (tid == 0) {                       // descending exclusive scan
            int acc = 0;
            for (int l = MAXLEN; l >= 0; --l) { base_s[l] = acc; acc += hist_s[l]; }
        }
        __syncthreads();
        if (gid < B) {
            const int slot = base_s[myLen] + atomicAdd(&cnt[myLen], 1);
            slotPacked[slot] = make_int2(myS0, (gid << 7) | myLen);
        }
        if (gid < nslots - B) slotPacked[B + gid] = make_int2(0, -128);
        grid.sync();                          // scatter complete
        sp = slotPacked;
    }

    // ---- Phase C: R2 main loop (unchanged) ----
    if (tid < NSEG) {
        const int slot = segbase + tid;
        int sg = -1, s = 0, len = 0;
        if (sp != nullptr) {
            const int2 p = sp[slot];
            s   = p.x;
            sg  = p.y >> 7;          // arithmetic: tail slots decode to -1
            len = p.y & 127;
        } else {
            const int b = slot;
            if (b < B) {
                sg = b;
                int lo = 0, hi = N;
                while (lo < hi) { int m = (lo + hi) >> 1; if (index[m] < b) lo = m + 1; else hi = m; }
                s = lo;
                hi = N;
                while (lo < hi) { int m = (lo + hi) >> 1; if (index[m] < b + 1) lo = m + 1; else hi = m; }
                len = lo - s;
                len = len < MAXLEN ? len : MAXLEN;
            }
        }
        sstart[tid] = s;
        slen[tid] = len;
        sseg[tid] = sg;
    }
    for (int i = tid; i < 2 * 16 * HSTR / 2; i += 256) ((int*)hst)[i] = 0;
    __syncthreads();

    // --- weight B-fragments (register-resident), PRE-SCALED by the exp2
    // factor; scaled bias becomes the per-gate MFMA C-seed bsv[g]. ---
    bf16x8 wi[4][2], wh[4][2];
    f32x4 bsv[4];
#pragma unroll
    for (int g = 0; g < 4; ++g) {
        const float sc = (g == 2) ? (-2.0f * L2E) : (-L2E);
        const int row = g * HDIM + ncol;
        const float bb = sc * (bih[row] + bhh[row]);
        bsv[g][0] = bb; bsv[g][1] = bb; bsv[g][2] = bb; bsv[g][3] = bb;
#pragma unroll
        for (int kt = 0; kt < 2; ++kt) {
            const f32x4* pi = (const f32x4*)(Wih + (size_t)row * HDIM + kt * 32 + quad * 8);
            const f32x4* ph = (const f32x4*)(Whh + (size_t)row * HDIM + kt * 32 + quad * 8);
            wi[g][kt] = pack8(pi[0] * sc, pi[1] * sc);
            wh[g][kt] = pack8(ph[0] * sc, ph[1] * sc);
        }
    }

    // Per-lane gate-math metadata: segs quad*3 + r, r in 0..2.
    int len3[3];
#pragma unroll
    for (int r = 0; r < 3; ++r) len3[r] = slen[quad * 3 + r];
    int lmax = 0;
#pragma unroll
    for (int i = 0; i < NSEG; ++i) { int v = slen[i]; lmax = v > lmax ? v : lmax; }
    lmax = __builtin_amdgcn_readfirstlane(lmax);

    // Staging roles: 12 segs x 4 steps x 4 col-groups(16 floats) = 192 units;
    // waves 0..2 stage (tid < 192), wave 3 idle in staging. pre = 16 VGPRs.
    const int sS = tid >> 4, sT = (tid >> 2) & 3, sC = tid & 3;   // valid for tid<192
    const int sst = (tid < 192) ? sstart[sS] : 0;
    const int sln = (tid < 192) ? slen[sS] : 0;

    f32x4 pre[4];

#define ISSUE(t0_)                                                              \
    if (w < 3) {                                                                \
        int ct = (t0_) + sT;                                                    \
        ct = (sln > 0) ? (ct < sln ? ct : sln - 1) : 0;                         \
        int row = sst + ct;                                                     \
        row = row < N - 1 ? row : N - 1;                                        \
        const f32x4* p_ = (const f32x4*)(x + (size_t)row * HDIM + sC * 16);     \
        pre[0] = p_[0]; pre[1] = p_[1]; pre[2] = p_[2]; pre[3] = p_[3];         \
    }
#define COMMIT()                                                                \
    if (w < 3) {                                                                \
        uint4 o1, o2;                                                           \
        o1.x = cvtpk(pre[0][0], pre[0][1]); o1.y = cvtpk(pre[0][2], pre[0][3]); \
        o1.z = cvtpk(pre[1][0], pre[1][1]); o1.w = cvtpk(pre[1][2], pre[1][3]); \
        o2.x = cvtpk(pre[2][0], pre[2][1]); o2.y = cvtpk(pre[2][2], pre[2][3]); \
        o2.z = cvtpk(pre[3][0], pre[3][1]); o2.w = cvtpk(pre[3][2], pre[3][3]); \
        unsigned short* d_ = &xst[sS * SPLANE + sT * SROW + sC * 16];           \
        *(uint4*)d_ = o1; *(uint4*)(d_ + 8) = o2;                               \
    }

    // x A-frag source plane for this lane's A-row m=l15: real seg
    // (m>>2)*3 + min(m&3,2); garbage rows alias a real plane (broadcast, free).
    const int m3 = l15 & 3;
    const int xp = (l15 >> 2) * 3 + (m3 < 2 ? m3 : 2);
    const unsigned short* xb = &xst[xp * SPLANE + quad * 8];

    // accx[g] = bias + x_t @ Wih' for the upcoming step (h-independent).
    f32x4 accx[4];
#define ACCX(tt_)                                                               \
    {                                                                           \
        const unsigned short* xr_ = xb + (tt_) * SROW;                          \
        bf16x8 xa0_ = *(const bf16x8*)(xr_);                                    \
        bf16x8 xa1_ = *(const bf16x8*)(xr_ + 32);                               \
        _Pragma("unroll")                                                       \
        for (int g_ = 0; g_ < 4; ++g_) {                                        \
            f32x4 a_ = __builtin_amdgcn_mfma_f32_16x16x32_bf16(xa0_, wi[g_][0], bsv[g_], 0, 0, 0); \
            accx[g_] = __builtin_amdgcn_mfma_f32_16x16x32_bf16(xa1_, wi[g_][1], a_, 0, 0, 0); \
        }                                                                       \
    }

    float c3[3] = {0, 0, 0}, h3[3] = {0, 0, 0};
    const int nch = (lmax + CH - 1) / CH;

    if (nch > 0) {
        ISSUE(0);
        COMMIT();                      // compiler auto-waits vmcnt for pre use
        LGKM_BARRIER();
        ACCX(0);                       // x-part of step 0
        if (nch > 1) ISSUE(CH);        // chunk 1 in flight across chunk 0's steps

        for (int ch = 0; ch < nch; ++ch) {
            const int t0 = ch * CH;
#pragma unroll
            for (int tt = 0; tt < CH; ++tt) {
                const int t = t0 + tt;          // parity(t) == parity(tt), CH even
                const int pb = tt & 1, nb = pb ^ 1;

                // h-dependent half: 2-deep chain seeded by accx.
                const unsigned short* hr = &hst[pb][l15][quad * 8];
                bf16x8 ha0 = *(const bf16x8*)(hr);
                bf16x8 ha1 = *(const bf16x8*)(hr + 32);

                f32x4 acc[4];
#pragma unroll
                for (int g = 0; g < 4; ++g) {
                    f32x4 a = __builtin_amdgcn_mfma_f32_16x16x32_bf16(ha0, wh[g][0], accx[g], 0, 0, 0);
                    acc[g] = __builtin_amdgcn_mfma_f32_16x16x32_bf16(ha1, wh[g][1], a, 0, 0, 0);
                }

                // x-part of the NEXT step (independent of h): fills the
                // MFMA pipe while this step's gate trans runs.
                if (tt + 1 < CH) ACCX(tt + 1);

                // Gate math: 3 real bundles/lane (C regs 0..2 = segs 3q..3q+2).
                // acc is pre-scaled (incl bias) -> activations are fma-free.
#pragma unroll
                for (int r = 0; r < 3; ++r) {
                    float gi = sig_pre (acc[0][r]);
                    float gf = sig_pre (acc[1][r]);
                    float gg = tanh_pre(acc[2][r]);
                    float go = sig_pre (acc[3][r]);
                    float cn = fmaf(gf, c3[r], gi * gg);
                    float hn = go * tanh_p(cn);
                    const bool up = t < len3[r];
                    c3[r] = up ? cn : c3[r];
                    h3[r] = up ? hn : h3[r];
                    hst[nb][quad * 4 + r][ncol] = (unsigned short)cvtpk(h3[r], h3[r]);
                }
                LGKM_BARRIER();
            }
            if (ch + 1 < nch) {
                COMMIT();                          // chunk ch+1 (vmcnt auto-waited)
                LGKM_BARRIER();
                ACCX(0);                           // x-part of next chunk's step 0
                if (ch + 2 < nch) ISSUE((ch + 2) * CH);
            }
        }
    }

#pragma unroll
    for (int r = 0; r < 3; ++r) {
        const int sg = sseg[quad * 3 + r];
        if (sg >= 0) out[(size_t)sg * HDIM + ncol] = h3[r];
    }
#undef ISSUE
#undef COMMIT
#undef ACCX
}

extern "C" void kernel_launch(void* const* d_in, const int* in_sizes, int n_in,
                              void* d_out, int out_size, void* d_ws, size_t ws_size,
                              hipStream_t stream) {
    const float* x   = (const float*)d_in[0];
    const float* Wih = (const float*)d_in[1];
    const float* Whh = (const float*)d_in[2];
    const float* bih = (const float*)d_in[3];
    const float* bhh = (const float*)d_in[4];
    const int* index = (const int*)d_in[5];

    int N = in_sizes[5];
    int B = out_size / HDIM;                     // 8192
    int nblocks = (B + NSEG - 1) / NSEG;         // 683
    const int nslots = nblocks * NSEG;

    // ws layout (ints): hist[128] | cnt[128] | slotPacked int2[nslots]
    const size_t need = (256 + 2 * (size_t)nslots) * sizeof(int);
    int* wsi = (int*)d_ws;
    float* outp = (float*)d_out;
    int doSort = (d_ws != nullptr && ws_size >= need) ? 1 : 0;

    bool launched = false;
    if (doSort) {
        void* args[] = {(void*)&x, (void*)&Wih, (void*)&Whh, (void*)&bih, (void*)&bhh,
                        (void*)&index, (void*)&wsi, (void*)&outp,
                        (void*)&N, (void*)&B, (void*)&doSort};
        hipError_t e = hipLaunchCooperativeKernel((const void*)lstm_coop_kernel,
                                                  dim3(nblocks), dim3(256),
                                                  args, 0, stream);
        if (e == hipSuccess) launched = true;
        else (void)hipGetLastError();            // clear; fall back to plain path
    }
    if (!launched) {
        lstm_coop_kernel<<<nblocks, 256, 0, stream>>>(x, Wih, Whh, bih, bhh, index,
                                                      wsi, outp, N, B, 0);
    }
}

// Round 5
// 235.617 us; speedup vs baseline: 1.9843x; 1.9843x over previous
//
#include <hip/hip_runtime.h>

#define MAXLEN 100
#define HDIM 64
#define CH 4                       // x-staging chunk length (steps)
#define NSEG 12                    // segments per block (12 real rows of 16)
#define SROW 72                    // ushorts per bf16 x step-row (144 B)
#define SPLANE (CH * SROW + 8)     // 296 ushorts per segment plane
#define HSTR 72                    // ushorts per h row (144 B)
#define L2E 1.44269504f

typedef __attribute__((ext_vector_type(8))) short bf16x8;
typedef __attribute__((ext_vector_type(4))) float f32x4;

// Step barrier: LDS-only consistency (no implicit vmcnt(0) drain), so the
// chunk-ahead x prefetch stays in flight across all step barriers.
#define LGKM_BARRIER() asm volatile("s_waitcnt lgkmcnt(0)\n\ts_barrier" ::: "memory")

// RNE f32x2 -> packed bf16x2 in one instruction (no builtin on gfx950).
__device__ __forceinline__ unsigned cvtpk(float a, float b) {
    unsigned r;
    asm("v_cvt_pk_bf16_f32 %0, %1, %2" : "=v"(r) : "v"(a), "v"(b));
    return r;
}
__device__ __forceinline__ bf16x8 pack8(f32x4 a, f32x4 b) {
    union { unsigned u[4]; bf16x8 v; } c;
    c.u[0] = cvtpk(a[0], a[1]); c.u[1] = cvtpk(a[2], a[3]);
    c.u[2] = cvtpk(b[0], b[1]); c.u[3] = cvtpk(b[2], b[3]);
    return c.v;
}
// Activations on PRE-SCALED pre-activations: -L2E (resp -2*L2E for gate g)
// is folded into the bf16 weights; the scaled bias is the MFMA C-seed.
__device__ __forceinline__ float sig_pre(float a) {     // a = -L2E*z
    return __builtin_amdgcn_rcpf(1.0f + __builtin_amdgcn_exp2f(a));
}
__device__ __forceinline__ float tanh_pre(float a) {    // a = -2*L2E*z
    return fmaf(2.0f, __builtin_amdgcn_rcpf(1.0f + __builtin_amdgcn_exp2f(a)), -1.0f);
}
__device__ __forceinline__ float tanh_p(float v) {      // v in true scale
    return fmaf(2.0f, __builtin_amdgcn_rcpf(1.0f + __builtin_amdgcn_exp2f(v * (-2.0f * L2E))), -1.0f);
}

// ---------------------------------------------------------------------------
// Pre-pass k1: thread s in [0,B] writes segStart[s] = lower_bound(index, s).
// Pure stores -> no workspace init required, no atomics. ~2-3 us.
// ---------------------------------------------------------------------------
__global__ void seg_bounds_kernel(const int* __restrict__ index,
                                  int* __restrict__ segStart, int N, int B) {
    const int s = blockIdx.x * blockDim.x + threadIdx.x;
    if (s > B) return;
    int lo = 0, hi = N;
    while (lo < hi) { int m = (lo + hi) >> 1; if (index[m] < s) lo = m + 1; else hi = m; }
    segStart[s] = lo;
}

// ---------------------------------------------------------------------------
// Pre-pass k2 (single block, 1024 threads): counting sort by length,
// descending, entirely with LDS counters (no global memset dependency).
// slotPacked[slot] = {start, (seg<<7)|len}; tail slots get seg=-1.
// Blocks of the main kernel take 12 consecutive slots -> ~equal lengths ->
// lmax ~= mean(len) instead of max-of-12 (-17% step work, R1-proven).
// ---------------------------------------------------------------------------
__global__ __launch_bounds__(1024)
void seg_sort_kernel(const int* __restrict__ segStart,
                     int2* __restrict__ slotPacked, int B, int nslots) {
    __shared__ int hist_s[MAXLEN + 1], base_s[MAXLEN + 1], cnt_s[MAXLEN + 1];
    const int tid = threadIdx.x;
    if (tid <= MAXLEN) { hist_s[tid] = 0; cnt_s[tid] = 0; }
    __syncthreads();
    int myS0[8], myLen[8];
#pragma unroll
    for (int j = 0; j < 8; ++j) {
        const int s = tid + j * 1024;
        myS0[j] = 0; myLen[j] = -1;
        if (s < B) {
            const int a = segStart[s];
            int len = segStart[s + 1] - a;
            len = len < MAXLEN ? len : MAXLEN;
            myS0[j] = a; myLen[j] = len;
            atomicAdd(&hist_s[len], 1);
        }
    }
    __syncthreads();
    if (tid == 0) {                      // descending exclusive scan, 101 iters
        int acc = 0;
        for (int l = MAXLEN; l >= 0; --l) { base_s[l] = acc; acc += hist_s[l]; }
    }
    __syncthreads();
#pragma unroll
    for (int j = 0; j < 8; ++j) {
        if (myLen[j] >= 0) {
            const int s = tid + j * 1024;
            const int slot = base_s[myLen[j]] + atomicAdd(&cnt_s[myLen[j]], 1);
            slotPacked[slot] = make_int2(myS0[j], (s << 7) | myLen[j]);
        }
    }
    if (tid < nslots - B) slotPacked[B + tid] = make_int2(0, -128);
}

// Main kernel — identical to R2's proven 80.6us loop.
// 683 blocks x 256 threads; 12 segments/block; 4 waves, wave w owns hidden
// cols [16w,16w+16) for all 4 gates. Segment s -> MFMA A/C row (s/3)*4+(s%3);
// each lane's C regs 0..2 are its 3 real (seg,hid) bundles.
// Per-step MFMA chain split: accx[g] = x_t @ Wih' (h-independent, seeded with
// the scaled bias) runs in the previous step's trans shadow; the serial step
// is acc = mfma(ha1,wh1, mfma(ha0,wh0,accx)).
__global__ __launch_bounds__(256, 3)
void lstm12_kernel(const float* __restrict__ x,
                   const float* __restrict__ Wih,
                   const float* __restrict__ Whh,
                   const float* __restrict__ bih,
                   const float* __restrict__ bhh,
                   const int* __restrict__ index,
                   const int2* __restrict__ slotPacked,
                   float* __restrict__ out, int N, int B) {
    const int tid  = threadIdx.x;
    const int w    = tid >> 6;
    const int lane = tid & 63;
    const int l15  = lane & 15;
    const int quad = lane >> 4;
    const int segbase = blockIdx.x * NSEG;
    const int ncol = w * 16 + l15;

    __shared__ __align__(16) unsigned short xst[NSEG * SPLANE];  // 7.1 KB
    __shared__ __align__(16) unsigned short hst[2][16][HSTR];    // 4.6 KB
    __shared__ int sstart[NSEG], slen[NSEG], sseg[NSEG];

    // --- per-block segment bounds: packed slots if available, else search ---
    if (tid < NSEG) {
        const int slot = segbase + tid;
        int sg = -1, s = 0, len = 0;
        if (slotPacked != nullptr) {
            const int2 p = slotPacked[slot];
            s   = p.x;
            sg  = p.y >> 7;          // arithmetic: tail slots decode to -1
            len = p.y & 127;
        } else {
            const int b = slot;
            if (b < B) {
                sg = b;
                int lo = 0, hi = N;
                while (lo < hi) { int m = (lo + hi) >> 1; if (index[m] < b) lo = m + 1; else hi = m; }
                s = lo;
                hi = N;
                while (lo < hi) { int m = (lo + hi) >> 1; if (index[m] < b + 1) lo = m + 1; else hi = m; }
                len = lo - s;
                len = len < MAXLEN ? len : MAXLEN;
            }
        }
        sstart[tid] = s;
        slen[tid] = len;
        sseg[tid] = sg;
    }
    for (int i = tid; i < 2 * 16 * HSTR / 2; i += 256) ((int*)hst)[i] = 0;
    __syncthreads();

    // --- weight B-fragments (register-resident), PRE-SCALED by the exp2
    // factor; scaled bias becomes the per-gate MFMA C-seed bsv[g]. ---
    bf16x8 wi[4][2], wh[4][2];
    f32x4 bsv[4];
#pragma unroll
    for (int g = 0; g < 4; ++g) {
        const float sc = (g == 2) ? (-2.0f * L2E) : (-L2E);
        const int row = g * HDIM + ncol;
        const float bb = sc * (bih[row] + bhh[row]);
        bsv[g][0] = bb; bsv[g][1] = bb; bsv[g][2] = bb; bsv[g][3] = bb;
#pragma unroll
        for (int kt = 0; kt < 2; ++kt) {
            const f32x4* pi = (const f32x4*)(Wih + (size_t)row * HDIM + kt * 32 + quad * 8);
            const f32x4* ph = (const f32x4*)(Whh + (size_t)row * HDIM + kt * 32 + quad * 8);
            wi[g][kt] = pack8(pi[0] * sc, pi[1] * sc);
            wh[g][kt] = pack8(ph[0] * sc, ph[1] * sc);
        }
    }

    // Per-lane gate-math metadata: segs quad*3 + r, r in 0..2.
    int len3[3];
#pragma unroll
    for (int r = 0; r < 3; ++r) len3[r] = slen[quad * 3 + r];
    int lmax = 0;
#pragma unroll
    for (int i = 0; i < NSEG; ++i) { int v = slen[i]; lmax = v > lmax ? v : lmax; }
    lmax = __builtin_amdgcn_readfirstlane(lmax);

    // Staging roles: 12 segs x 4 steps x 4 col-groups(16 floats) = 192 units;
    // waves 0..2 stage (tid < 192), wave 3 idle in staging. pre = 16 VGPRs.
    const int sS = tid >> 4, sT = (tid >> 2) & 3, sC = tid & 3;   // valid for tid<192
    const int sst = (tid < 192) ? sstart[sS] : 0;
    const int sln = (tid < 192) ? slen[sS] : 0;

    f32x4 pre[4];

#define ISSUE(t0_)                                                              \
    if (w < 3) {                                                                \
        int ct = (t0_) + sT;                                                    \
        ct = (sln > 0) ? (ct < sln ? ct : sln - 1) : 0;                         \
        int row = sst + ct;                                                     \
        row = row < N - 1 ? row : N - 1;                                        \
        const f32x4* p_ = (const f32x4*)(x + (size_t)row * HDIM + sC * 16);     \
        pre[0] = p_[0]; pre[1] = p_[1]; pre[2] = p_[2]; pre[3] = p_[3];         \
    }
#define COMMIT()                                                                \
    if (w < 3) {                                                                \
        uint4 o1, o2;                                                           \
        o1.x = cvtpk(pre[0][0], pre[0][1]); o1.y = cvtpk(pre[0][2], pre[0][3]); \
        o1.z = cvtpk(pre[1][0], pre[1][1]); o1.w = cvtpk(pre[1][2], pre[1][3]); \
        o2.x = cvtpk(pre[2][0], pre[2][1]); o2.y = cvtpk(pre[2][2], pre[2][3]); \
        o2.z = cvtpk(pre[3][0], pre[3][1]); o2.w = cvtpk(pre[3][2], pre[3][3]); \
        unsigned short* d_ = &xst[sS * SPLANE + sT * SROW + sC * 16];           \
        *(uint4*)d_ = o1; *(uint4*)(d_ + 8) = o2;                               \
    }

    // x A-frag source plane for this lane's A-row m=l15: real seg
    // (m>>2)*3 + min(m&3,2); garbage rows alias a real plane (broadcast, free).
    const int m3 = l15 & 3;
    const int xp = (l15 >> 2) * 3 + (m3 < 2 ? m3 : 2);
    const unsigned short* xb = &xst[xp * SPLANE + quad * 8];

    // accx[g] = bias + x_t @ Wih' for the upcoming step (h-independent).
    f32x4 accx[4];
#define ACCX(tt_)                                                               \
    {                                                                           \
        const unsigned short* xr_ = xb + (tt_) * SROW;                          \
        bf16x8 xa0_ = *(const bf16x8*)(xr_);                                    \
        bf16x8 xa1_ = *(const bf16x8*)(xr_ + 32);                               \
        _Pragma("unroll")                                                       \
        for (int g_ = 0; g_ < 4; ++g_) {                                        \
            f32x4 a_ = __builtin_amdgcn_mfma_f32_16x16x32_bf16(xa0_, wi[g_][0], bsv[g_], 0, 0, 0); \
            accx[g_] = __builtin_amdgcn_mfma_f32_16x16x32_bf16(xa1_, wi[g_][1], a_, 0, 0, 0); \
        }                                                                       \
    }

    float c3[3] = {0, 0, 0}, h3[3] = {0, 0, 0};
    const int nch = (lmax + CH - 1) / CH;

    if (nch > 0) {
        ISSUE(0);
        COMMIT();                      // compiler auto-waits vmcnt for pre use
        LGKM_BARRIER();
        ACCX(0);                       // x-part of step 0
        if (nch > 1) ISSUE(CH);        // chunk 1 in flight across chunk 0's steps

        for (int ch = 0; ch < nch; ++ch) {
            const int t0 = ch * CH;
#pragma unroll
            for (int tt = 0; tt < CH; ++tt) {
                const int t = t0 + tt;          // parity(t) == parity(tt), CH even
                const int pb = tt & 1, nb = pb ^ 1;

                // h-dependent half: 2-deep chain seeded by accx.
                const unsigned short* hr = &hst[pb][l15][quad * 8];
                bf16x8 ha0 = *(const bf16x8*)(hr);
                bf16x8 ha1 = *(const bf16x8*)(hr + 32);

                f32x4 acc[4];
#pragma unroll
                for (int g = 0; g < 4; ++g) {
                    f32x4 a = __builtin_amdgcn_mfma_f32_16x16x32_bf16(ha0, wh[g][0], accx[g], 0, 0, 0);
                    acc[g] = __builtin_amdgcn_mfma_f32_16x16x32_bf16(ha1, wh[g][1], a, 0, 0, 0);
                }

                // x-part of the NEXT step (independent of h): fills the
                // MFMA pipe while this step's gate trans runs.
                if (tt + 1 < CH) ACCX(tt + 1);

                // Gate math: 3 real bundles/lane (C regs 0..2 = segs 3q..3q+2).
                // acc is pre-scaled (incl bias) -> activations are fma-free.
#pragma unroll
                for (int r = 0; r < 3; ++r) {
                    float gi = sig_pre (acc[0][r]);
                    float gf = sig_pre (acc[1][r]);
                    float gg = tanh_pre(acc[2][r]);
                    float go = sig_pre (acc[3][r]);
                    float cn = fmaf(gf, c3[r], gi * gg);
                    float hn = go * tanh_p(cn);
                    const bool up = t < len3[r];
                    c3[r] = up ? cn : c3[r];
                    h3[r] = up ? hn : h3[r];
                    hst[nb][quad * 4 + r][ncol] = (unsigned short)cvtpk(h3[r], h3[r]);
                }
                LGKM_BARRIER();
            }
            if (ch + 1 < nch) {
                COMMIT();                          // chunk ch+1 (vmcnt auto-waited)
                LGKM_BARRIER();
                ACCX(0);                           // x-part of next chunk's step 0
                if (ch + 2 < nch) ISSUE((ch + 2) * CH);
            }
        }
    }

#pragma unroll
    for (int r = 0; r < 3; ++r) {
        const int sg = sseg[quad * 3 + r];
        if (sg >= 0) out[(size_t)sg * HDIM + ncol] = h3[r];
    }
#undef ISSUE
#undef COMMIT
#undef ACCX
}

extern "C" void kernel_launch(void* const* d_in, const int* in_sizes, int n_in,
                              void* d_out, int out_size, void* d_ws, size_t ws_size,
                              hipStream_t stream) {
    const float* x   = (const float*)d_in[0];
    const float* Wih = (const float*)d_in[1];
    const float* Whh = (const float*)d_in[2];
    const float* bih = (const float*)d_in[3];
    const float* bhh = (const float*)d_in[4];
    const int* index = (const int*)d_in[5];

    const int N = in_sizes[5];
    const int B = out_size / HDIM;               // 8192
    const int nblocks = (B + NSEG - 1) / NSEG;   // 683
    const int nslots = nblocks * NSEG;           // 8196

    // ws layout (ints): segStart[B+1] (pad to 8) | slotPacked int2[nslots]
    int slotOfs = (B + 1 + 7) & ~7;
    const size_t need = ((size_t)slotOfs + 2 * (size_t)nslots) * sizeof(int);
    const bool sortOK = (d_ws != nullptr) && (ws_size >= need) && (B <= 8192);

    if (sortOK) {
        int* segStart = (int*)d_ws;
        int2* slotPacked = (int2*)((int*)d_ws + slotOfs);
        const int k1blocks = (B + 1 + 255) / 256;   // 33
        seg_bounds_kernel<<<k1blocks, 256, 0, stream>>>(index, segStart, N, B);
        seg_sort_kernel<<<1, 1024, 0, stream>>>(segStart, slotPacked, B, nslots);
        lstm12_kernel<<<nblocks, 256, 0, stream>>>(x, Wih, Whh, bih, bhh, index,
                                                   slotPacked, (float*)d_out, N, B);
    } else {
        lstm12_kernel<<<nblocks, 256, 0, stream>>>(x, Wih, Whh, bih, bhh, index,
                                                   nullptr, (float*)d_out, N, B);
    }
}

// Round 7
// 232.373 us; speedup vs baseline: 2.0120x; 1.0140x over previous
//
#include <hip/hip_runtime.h>

#define MAXLEN 100
#define HDIM 64
#define CH 4                       // x-staging chunk length (steps)
#define NSEG 16                    // segments per block (all 16 MFMA rows real)
#define SROW 72                    // ushorts per bf16 x step-row (144 B)
#define SPLANE (CH * SROW + 8)     // 296 ushorts per segment plane
#define HSTR 72                    // ushorts per h row (144 B)
#define L2E 1.44269504f

typedef __attribute__((ext_vector_type(8))) short bf16x8;
typedef __attribute__((ext_vector_type(4))) float f32x4;

// Step barrier: LDS-only consistency (no implicit vmcnt(0) drain), so the
// chunk-ahead x prefetch stays in flight across all step barriers.
#define LGKM_BARRIER() asm volatile("s_waitcnt lgkmcnt(0)\n\ts_barrier" ::: "memory")

// RNE f32x2 -> packed bf16x2 in one instruction (no builtin on gfx950).
__device__ __forceinline__ unsigned cvtpk(float a, float b) {
    unsigned r;
    asm("v_cvt_pk_bf16_f32 %0, %1, %2" : "=v"(r) : "v"(a), "v"(b));
    return r;
}
__device__ __forceinline__ bf16x8 pack8(f32x4 a, f32x4 b) {
    union { unsigned u[4]; bf16x8 v; } c;
    c.u[0] = cvtpk(a[0], a[1]); c.u[1] = cvtpk(a[2], a[3]);
    c.u[2] = cvtpk(b[0], b[1]); c.u[3] = cvtpk(b[2], b[3]);
    return c.v;
}
// Activations on PRE-SCALED pre-activations: -L2E (resp -2*L2E for gate g)
// is folded into the bf16 weights; the scaled bias is the MFMA C-seed.
__device__ __forceinline__ float sig_pre(float a) {     // a = -L2E*z
    return __builtin_amdgcn_rcpf(1.0f + __builtin_amdgcn_exp2f(a));
}
__device__ __forceinline__ float tanh_pre(float a) {    // a = -2*L2E*z
    return fmaf(2.0f, __builtin_amdgcn_rcpf(1.0f + __builtin_amdgcn_exp2f(a)), -1.0f);
}
__device__ __forceinline__ float tanh_p(float v) {      // v in true scale
    return fmaf(2.0f, __builtin_amdgcn_rcpf(1.0f + __builtin_amdgcn_exp2f(v * (-2.0f * L2E))), -1.0f);
}

// ---------------------------------------------------------------------------
// Pre-pass k1: thread s in [0,B] writes segStart[s] = lower_bound(index, s).
// Pure stores -> no workspace init required, no atomics. ~2-3 us.
// ---------------------------------------------------------------------------
__global__ void seg_bounds_kernel(const int* __restrict__ index,
                                  int* __restrict__ segStart, int N, int B) {
    const int s = blockIdx.x * blockDim.x + threadIdx.x;
    if (s > B) return;
    int lo = 0, hi = N;
    while (lo < hi) { int m = (lo + hi) >> 1; if (index[m] < s) lo = m + 1; else hi = m; }
    segStart[s] = lo;
}

// ---------------------------------------------------------------------------
// Pre-pass k2 (single block, 1024 threads): counting sort by length,
// descending, entirely with LDS counters (no global memset dependency).
// slotPacked[slot] = {start, (seg<<7)|len}; tail slots get seg=-1.
// Blocks of the main kernel take 16 consecutive slots -> ~equal lengths ->
// lmax ~= mean(len) instead of max-of-NSEG (R1/R5-proven).
// ---------------------------------------------------------------------------
__global__ __launch_bounds__(1024)
void seg_sort_kernel(const int* __restrict__ segStart,
                     int2* __restrict__ slotPacked, int B, int nslots) {
    __shared__ int hist_s[MAXLEN + 1], base_s[MAXLEN + 1], cnt_s[MAXLEN + 1];
    const int tid = threadIdx.x;
    if (tid <= MAXLEN) { hist_s[tid] = 0; cnt_s[tid] = 0; }
    __syncthreads();
    int myS0[8], myLen[8];
#pragma unroll
    for (int j = 0; j < 8; ++j) {
        const int s = tid + j * 1024;
        myS0[j] = 0; myLen[j] = -1;
        if (s < B) {
            const int a = segStart[s];
            int len = segStart[s + 1] - a;
            len = len < MAXLEN ? len : MAXLEN;
            myS0[j] = a; myLen[j] = len;
            atomicAdd(&hist_s[len], 1);
        }
    }
    __syncthreads();
    if (tid == 0) {                      // descending exclusive scan, 101 iters
        int acc = 0;
        for (int l = MAXLEN; l >= 0; --l) { base_s[l] = acc; acc += hist_s[l]; }
    }
    __syncthreads();
#pragma unroll
    for (int j = 0; j < 8; ++j) {
        if (myLen[j] >= 0) {
            const int s = tid + j * 1024;
            const int slot = base_s[myLen[j]] + atomicAdd(&cnt_s[myLen[j]], 1);
            slotPacked[slot] = make_int2(myS0[j], (s << 7) | myLen[j]);
        }
    }
    if (tid < nslots - B) slotPacked[B + tid] = make_int2(0, -128);
}

// Main kernel — NSEG=16 variant of the proven R2/R5 loop (80.0 us there).
// 512 blocks x 256 threads; 16 segments/block (seg s -> MFMA A/C row s,
// NO aliased rows: -25% total MFMA work vs NSEG=12) and exactly 2 blocks/CU
// (vs 2.67: the critical len~100 block shares its CU with one ~mean-length
// block instead of two). 4 waves; wave w owns hidden cols [16w,16w+16) for
// all 4 gates; each lane's C regs 0..3 are its 4 real (seg,hid) cells.
// Per-step MFMA chain split: accx[g] = x_t @ Wih' (h-independent, seeded
// with the scaled bias) runs in the previous step's trans shadow; the serial
// step is acc = mfma(ha1,wh1, mfma(ha0,wh0,accx)).
__global__ __launch_bounds__(256, 2)
void lstm16_kernel(const float* __restrict__ x,
                   const float* __restrict__ Wih,
                   const float* __restrict__ Whh,
                   const float* __restrict__ bih,
                   const float* __restrict__ bhh,
                   const int* __restrict__ index,
                   const int2* __restrict__ slotPacked,
                   float* __restrict__ out, int N, int B) {
    const int tid  = threadIdx.x;
    const int w    = tid >> 6;
    const int lane = tid & 63;
    const int l15  = lane & 15;
    const int quad = lane >> 4;
    const int segbase = blockIdx.x * NSEG;
    const int ncol = w * 16 + l15;

    __shared__ __align__(16) unsigned short xst[NSEG * SPLANE];  // 9.5 KB
    __shared__ __align__(16) unsigned short hst[2][16][HSTR];    // 4.6 KB
    __shared__ int sstart[NSEG], slen[NSEG], sseg[NSEG];

    // --- per-block segment bounds: packed slots if available, else search ---
    if (tid < NSEG) {
        const int slot = segbase + tid;
        int sg = -1, s = 0, len = 0;
        if (slotPacked != nullptr) {
            const int2 p = slotPacked[slot];
            s   = p.x;
            sg  = p.y >> 7;          // arithmetic: tail slots decode to -1
            len = p.y & 127;
        } else {
            const int b = slot;
            if (b < B) {
                sg = b;
                int lo = 0, hi = N;
                while (lo < hi) { int m = (lo + hi) >> 1; if (index[m] < b) lo = m + 1; else hi = m; }
                s = lo;
                hi = N;
                while (lo < hi) { int m = (lo + hi) >> 1; if (index[m] < b + 1) lo = m + 1; else hi = m; }
                len = lo - s;
                len = len < MAXLEN ? len : MAXLEN;
            }
        }
        sstart[tid] = s;
        slen[tid] = len;
        sseg[tid] = sg;
    }
    for (int i = tid; i < 2 * 16 * HSTR / 2; i += 256) ((int*)hst)[i] = 0;
    __syncthreads();

    // --- weight B-fragments (register-resident), PRE-SCALED by the exp2
    // factor; scaled bias becomes the per-gate MFMA C-seed bsv[g]. ---
    bf16x8 wi[4][2], wh[4][2];
    f32x4 bsv[4];
#pragma unroll
    for (int g = 0; g < 4; ++g) {
        const float sc = (g == 2) ? (-2.0f * L2E) : (-L2E);
        const int row = g * HDIM + ncol;
        const float bb = sc * (bih[row] + bhh[row]);
        bsv[g][0] = bb; bsv[g][1] = bb; bsv[g][2] = bb; bsv[g][3] = bb;
#pragma unroll
        for (int kt = 0; kt < 2; ++kt) {
            const f32x4* pi = (const f32x4*)(Wih + (size_t)row * HDIM + kt * 32 + quad * 8);
            const f32x4* ph = (const f32x4*)(Whh + (size_t)row * HDIM + kt * 32 + quad * 8);
            wi[g][kt] = pack8(pi[0] * sc, pi[1] * sc);
            wh[g][kt] = pack8(ph[0] * sc, ph[1] * sc);
        }
    }

    // Per-lane gate-math metadata: segs quad*4 + r, r in 0..3.
    int len4[4];
#pragma unroll
    for (int r = 0; r < 4; ++r) len4[r] = slen[quad * 4 + r];
    int lmax = 0;
#pragma unroll
    for (int i = 0; i < NSEG; ++i) { int v = slen[i]; lmax = v > lmax ? v : lmax; }
    lmax = __builtin_amdgcn_readfirstlane(lmax);

    // Staging roles: 16 segs x 4 steps x 4 col-groups(16 floats) = 256 units;
    // ALL 256 threads stage (no idle wave). pre = 16 VGPRs.
    const int sS = tid >> 4, sT = (tid >> 2) & 3, sC = tid & 3;
    const int sst = sstart[sS];
    const int sln = slen[sS];

    f32x4 pre[4];

#define ISSUE(t0_)                                                              \
    {                                                                           \
        int ct = (t0_) + sT;                                                    \
        ct = (sln > 0) ? (ct < sln ? ct : sln - 1) : 0;                         \
        int row = sst + ct;                                                     \
        row = row < N - 1 ? row : N - 1;                                        \
        const f32x4* p_ = (const f32x4*)(x + (size_t)row * HDIM + sC * 16);     \
        pre[0] = p_[0]; pre[1] = p_[1]; pre[2] = p_[2]; pre[3] = p_[3];         \
    }
#define COMMIT()                                                                \
    {                                                                           \
        uint4 o1, o2;                                                           \
        o1.x = cvtpk(pre[0][0], pre[0][1]); o1.y = cvtpk(pre[0][2], pre[0][3]); \
        o1.z = cvtpk(pre[1][0], pre[1][1]); o1.w = cvtpk(pre[1][2], pre[1][3]); \
        o2.x = cvtpk(pre[2][0], pre[2][1]); o2.y = cvtpk(pre[2][2], pre[2][3]); \
        o2.z = cvtpk(pre[3][0], pre[3][1]); o2.w = cvtpk(pre[3][2], pre[3][3]); \
        unsigned short* d_ = &xst[sS * SPLANE + sT * SROW + sC * 16];           \
        *(uint4*)d_ = o1; *(uint4*)(d_ + 8) = o2;                               \
    }

    // x A-frag source plane for this lane's A-row m=l15: seg l15 directly
    // (all 16 rows real at NSEG=16).
    const unsigned short* xb = &xst[l15 * SPLANE + quad * 8];

    // accx[g] = bias + x_t @ Wih' for the upcoming step (h-independent).
    f32x4 accx[4];
#define ACCX(tt_)                                                               \
    {                                                                           \
        const unsigned short* xr_ = xb + (tt_) * SROW;                          \
        bf16x8 xa0_ = *(const bf16x8*)(xr_);                                    \
        bf16x8 xa1_ = *(const bf16x8*)(xr_ + 32);                               \
        _Pragma("unroll")                                                       \
        for (int g_ = 0; g_ < 4; ++g_) {                                        \
            f32x4 a_ = __builtin_amdgcn_mfma_f32_16x16x32_bf16(xa0_, wi[g_][0], bsv[g_], 0, 0, 0); \
            accx[g_] = __builtin_amdgcn_mfma_f32_16x16x32_bf16(xa1_, wi[g_][1], a_, 0, 0, 0); \
        }                                                                       \
    }

    float c4[4] = {0, 0, 0, 0}, h4[4] = {0, 0, 0, 0};
    const int nch = (lmax + CH - 1) / CH;

    if (nch > 0) {
        ISSUE(0);
        COMMIT();                      // compiler auto-waits vmcnt for pre use
        LGKM_BARRIER();
        ACCX(0);                       // x-part of step 0
        if (nch > 1) ISSUE(CH);        // chunk 1 in flight across chunk 0's steps

        for (int ch = 0; ch < nch; ++ch) {
            const int t0 = ch * CH;
#pragma unroll
            for (int tt = 0; tt < CH; ++tt) {
                const int t = t0 + tt;          // parity(t) == parity(tt), CH even
                const int pb = tt & 1, nb = pb ^ 1;

                // h-dependent half: 2-deep chain seeded by accx.
                const unsigned short* hr = &hst[pb][l15][quad * 8];
                bf16x8 ha0 = *(const bf16x8*)(hr);
                bf16x8 ha1 = *(const bf16x8*)(hr + 32);

                f32x4 acc[4];
#pragma unroll
                for (int g = 0; g < 4; ++g) {
                    f32x4 a = __builtin_amdgcn_mfma_f32_16x16x32_bf16(ha0, wh[g][0], accx[g], 0, 0, 0);
                    acc[g] = __builtin_amdgcn_mfma_f32_16x16x32_bf16(ha1, wh[g][1], a, 0, 0, 0);
                }

                // x-part of the NEXT step (independent of h): fills the
                // MFMA pipe while this step's gate trans runs.
                if (tt + 1 < CH) ACCX(tt + 1);

                // Gate math: 4 real cells/lane (C regs 0..3 = segs 4q..4q+3).
                // acc is pre-scaled (incl bias) -> activations are fma-free.
#pragma unroll
                for (int r = 0; r < 4; ++r) {
                    float gi = sig_pre (acc[0][r]);
                    float gf = sig_pre (acc[1][r]);
                    float gg = tanh_pre(acc[2][r]);
                    float go = sig_pre (acc[3][r]);
                    float cn = fmaf(gf, c4[r], gi * gg);
                    float hn = go * tanh_p(cn);
                    const bool up = t < len4[r];
                    c4[r] = up ? cn : c4[r];
                    h4[r] = up ? hn : h4[r];
                    hst[nb][quad * 4 + r][ncol] = (unsigned short)cvtpk(h4[r], h4[r]);
                }
                LGKM_BARRIER();
            }
            if (ch + 1 < nch) {
                COMMIT();                          // chunk ch+1 (vmcnt auto-waited)
                LGKM_BARRIER();
                ACCX(0);                           // x-part of next chunk's step 0
                if (ch + 2 < nch) ISSUE((ch + 2) * CH);
            }
        }
    }

#pragma unroll
    for (int r = 0; r < 4; ++r) {
        const int sg = sseg[quad * 4 + r];
        if (sg >= 0) out[(size_t)sg * HDIM + ncol] = h4[r];
    }
#undef ISSUE
#undef COMMIT
#undef ACCX
}

extern "C" void kernel_launch(void* const* d_in, const int* in_sizes, int n_in,
                              void* d_out, int out_size, void* d_ws, size_t ws_size,
                              hipStream_t stream) {
    const float* x   = (const float*)d_in[0];
    const float* Wih = (const float*)d_in[1];
    const float* Whh = (const float*)d_in[2];
    const float* bih = (const float*)d_in[3];
    const float* bhh = (const float*)d_in[4];
    const int* index = (const int*)d_in[5];

    const int N = in_sizes[5];
    const int B = out_size / HDIM;               // 8192
    const int nblocks = (B + NSEG - 1) / NSEG;   // 512
    const int nslots = nblocks * NSEG;           // 8192

    // ws layout (ints): segStart[B+1] (pad to 8) | slotPacked int2[nslots]
    int slotOfs = (B + 1 + 7) & ~7;
    const size_t need = ((size_t)slotOfs + 2 * (size_t)nslots) * sizeof(int);
    const bool sortOK = (d_ws != nullptr) && (ws_size >= need) && (B <= 8192);

    if (sortOK) {
        int* segStart = (int*)d_ws;
        int2* slotPacked = (int2*)((int*)d_ws + slotOfs);
        const int k1blocks = (B + 1 + 255) / 256;   // 33
        seg_bounds_kernel<<<k1blocks, 256, 0, stream>>>(index, segStart, N, B);
        seg_sort_kernel<<<1, 1024, 0, stream>>>(segStart, slotPacked, B, nslots);
        lstm16_kernel<<<nblocks, 256, 0, stream>>>(x, Wih, Whh, bih, bhh, index,
                                                   slotPacked, (float*)d_out, N, B);
    } else {
        lstm16_kernel<<<nblocks, 256, 0, stream>>>(x, Wih, Whh, bih, bhh, index,
                                                   nullptr, (float*)d_out, N, B);
    }
}